// Round 10
// baseline (150.120 us; speedup 1.0000x reference)
//
#include <hip/hip_runtime.h>
#include <hip/hip_bf16.h>
#include <math.h>

// Polynomial feature map: Xp = X @ P; out = [bias | Xp | Xp^2 | Xp^3 | pairs | sqrt(|Xp|+eps)]
// X: [16384, 2048] f32, P: [2048, 512] f32, out: [16384, 2561] f32.
// pairs (triu k=1, first 512): c<511 -> Xp[:,0]*Xp[:,c+1]; c==511 -> Xp[:,1]*Xp[:,2]
//
// Fast path: prep_b (P -> Bt bf16) + xcvt (X -> Xb bf16) in ws; gemm10 = glds-only
// staging + split-K=2 + 3-buffer lead-2 COUNTED-vmcnt pipeline (never vmcnt(0) in the
// main loop -- clean ledger, no vmem register consumers); epi2_k sums partials and
// expands features.

typedef __attribute__((ext_vector_type(4))) float f32x4;
typedef __attribute__((ext_vector_type(8))) short bf16x8;

#define MM 16384
#define NN 512
#define KK 2048
#define OUTW 2561

#define BM 128
#define BN 128
#define BK 32
#define KH (KK / 2)       // 1024 per k-slice
#define NT2 (KH / BK)     // 32 steps

__device__ __forceinline__ short f2bf(float x) {
  union { __hip_bfloat16 b; short s; } u;
  u.b = __float2bfloat16(x);  // hw RNE; compiler pairs into v_cvt_pk_bf16_f32
  return u.s;
}

__device__ __forceinline__ bf16x8 cvt8(f32x4 a, f32x4 b) {
  bf16x8 r;
  r[0] = f2bf(a[0]); r[1] = f2bf(a[1]); r[2] = f2bf(a[2]); r[3] = f2bf(a[3]);
  r[4] = f2bf(b[0]); r[5] = f2bf(b[1]); r[6] = f2bf(b[2]); r[7] = f2bf(b[3]);
  return r;
}

__device__ __forceinline__ void gl_lds16(const void* g, void* l) {
  __builtin_amdgcn_global_load_lds((const __attribute__((address_space(1))) unsigned int*)g,
                                   (__attribute__((address_space(3))) unsigned int*)l, 16, 0, 0);
}

// ---------------- prep: P [K][N] f32 -> Bt [N][K] bf16 ----------------
__global__ __launch_bounds__(256) void prep_b(const float* __restrict__ P, short* __restrict__ Bt) {
  __shared__ float ts[64][65];
  const int tid = threadIdx.x;
  const int k0 = (blockIdx.x >> 3) * 64;  // 32 k-blocks
  const int n0 = (blockIdx.x & 7) * 64;   // 8 n-blocks
#pragma unroll
  for (int j = 0; j < 16; ++j) {
    int idx = j * 256 + tid;
    int kr = idx >> 6, nc = idx & 63;
    ts[kr][nc] = P[(size_t)(k0 + kr) * NN + n0 + nc];
  }
  __syncthreads();
#pragma unroll
  for (int j = 0; j < 16; ++j) {
    int idx = j * 256 + tid;
    int nr = idx >> 6, kc = idx & 63;
    Bt[(size_t)(n0 + nr) * KK + k0 + kc] = f2bf(ts[kc][nr]);
  }
}

// ---------------- xcvt: X [M][K] f32 -> Xb [M][K] bf16 ----------------
__global__ __launch_bounds__(256) void xcvt(const float* __restrict__ X, short* __restrict__ Xb) {
  size_t i = ((size_t)blockIdx.x * 256 + threadIdx.x) * 8;  // grid covers 33.55M elems
  f32x4 a = *(const f32x4*)(X + i);
  f32x4 b = *(const f32x4*)(X + i + 4);
  *(bf16x8*)(Xb + i) = cvt8(a, b);
}

// ---------------- GEMM: glds-only staging + split-K=2 + counted vmcnt ----------------
// LDS tiles [row][32 bf16] (64B rows, 4x 16B slots), phys slot = k-slot ^ ((row>>1)&3)
// -- measured 0 bank conflicts (r3/r4/r6/r8). Both A and B staged only by
// global_load_lds (linear dest); swizzle realized by permuting the per-lane GLOBAL
// source k-slot kd = (lane&3)^((lane>>3)&3) (rule #21).
//
// vmcnt ledger (the ONLY vmem ops are 4 glds/iter; no vmem register consumers, so the
// manual counts are authoritative):
//   prologue: stage(0->buf0) + stage(1->buf1)            -> outstanding 8
//   iter t:   s_waitcnt vmcnt(4)   [retires iter-t's 4]
//             s_barrier            [iter-t tile fully in LDS for all waves;
//                                   all waves done reading buf[(t-1)%3] since iter t-1]
//             stage(t+2 -> buf[(t+2)%3])                  -> outstanding 8 again
//             compute(buf[t%3])
//   tail:     t=NT-2 waits vmcnt(4) (no stage); t=NT-1 waits vmcnt(0).
__global__ __launch_bounds__(256, 4) void gemm10(const short* __restrict__ Xb,
                                                 const short* __restrict__ Bt,
                                                 float* __restrict__ out) {
  __shared__ short As[3][BM * BK];   // 8 KB each
  __shared__ short Bs[3][BN * BK];   // 8 KB each  (48 KB total -> 3 blocks/CU)

  const int tid = threadIdx.x;
  const int wid = tid >> 6, lane = tid & 63;
  const int lrow = lane & 15, kh = lane >> 4;
  const int wr = wid >> 1, wc = wid & 1;  // 2x2 wave grid; wave tile 64 x 64

  // XCD-bijective swizzle over 1024 blocks (1024%8==0). s<512 -> ks=0 (XCDs 0-3),
  // s>=512 -> ks=1 (XCDs 4-7): each XCD's K-half of Bt (1 MB) fits its private L2.
  const int bid = blockIdx.x;
  const int s = (bid & 7) * 128 + (bid >> 3);
  const int ks = s >> 9;
  const int tile = s & 511;
  const int m0 = (tile >> 2) * BM;   // 128 row-blocks
  const int n0 = (tile & 3) * BN;    // 4 col-blocks (consecutive tiles share A rows)
  const int kb = ks * KH;

  // staging descriptors: 2 A-loads + 2 B-loads per wave; load p covers rows (p*4+wid)*16..+15
  const int kd = (lane & 3) ^ ((lane >> 3) & 3);  // pre-swizzled source k-slot
  const short* aG[2];
  const short* bG[2];
  int tOff[2];
#pragma unroll
  for (int p = 0; p < 2; ++p) {
    int R0 = (p * 4 + wid) * 16;
    tOff[p] = R0 * 32;  // linear dest (shorts); hw adds lane*16B
    aG[p] = Xb + (size_t)(m0 + R0 + (lane >> 2)) * KK + kb + kd * 8;
    bG[p] = Bt + (size_t)(n0 + R0 + (lane >> 2)) * KK + kb + kd * 8;
  }

  f32x4 acc[4][4];
#pragma unroll
  for (int m = 0; m < 4; ++m)
#pragma unroll
    for (int n = 0; n < 4; ++n) acc[m][n] = (f32x4)0.0f;

  auto stage = [&](int t, int b) {
#pragma unroll
    for (int p = 0; p < 2; ++p) gl_lds16(aG[p] + (size_t)t * BK, &As[b][tOff[p]]);
#pragma unroll
    for (int p = 0; p < 2; ++p) gl_lds16(bG[p] + (size_t)t * BK, &Bs[b][tOff[p]]);
  };
  auto compute = [&](int b) {
    const int sw = (lrow >> 1) & 3;
    bf16x8 af[4], bfr[4];
#pragma unroll
    for (int m = 0; m < 4; ++m) {
      int r = wr * 64 + m * 16 + lrow;
      af[m] = *(const bf16x8*)&As[b][r * 32 + ((kh ^ sw) << 3)];
    }
#pragma unroll
    for (int n = 0; n < 4; ++n) {
      int r = wc * 64 + n * 16 + lrow;
      bfr[n] = *(const bf16x8*)&Bs[b][r * 32 + ((kh ^ sw) << 3)];
    }
#pragma unroll
    for (int m = 0; m < 4; ++m)
#pragma unroll
      for (int n = 0; n < 4; ++n)
        acc[m][n] = __builtin_amdgcn_mfma_f32_16x16x32_bf16(af[m], bfr[n], acc[m][n], 0, 0, 0);
  };

  // ---- prologue: 2 tiles in flight ----
  stage(0, 0);
  stage(1, 1);

  // ---- main loop: steady vmcnt(4), one raw barrier per K-step ----
  for (int t = 0; t < NT2 - 2; ++t) {
    asm volatile("s_waitcnt vmcnt(4)" ::: "memory");
    __builtin_amdgcn_s_barrier();
    int b2 = t + 2; b2 -= (b2 >= 3) ? 3 : 0; b2 -= (b2 >= 3) ? 3 : 0;  // (t+2)%3 cheap
    stage(t + 2, (t + 2) % 3);
    compute(t % 3);
  }
  // tail: t = NT2-2
  asm volatile("s_waitcnt vmcnt(4)" ::: "memory");
  __builtin_amdgcn_s_barrier();
  compute((NT2 - 2) % 3);
  // tail: t = NT2-1
  asm volatile("s_waitcnt vmcnt(0)" ::: "memory");
  __builtin_amdgcn_s_barrier();
  compute((NT2 - 1) % 3);

  // ---- write partial Xp into region ks (C/D layout: col = lane&15, row = kh*4 + reg) ----
#pragma unroll
  for (int m = 0; m < 4; ++m)
#pragma unroll
    for (int n = 0; n < 4; ++n)
#pragma unroll
      for (int r = 0; r < 4; ++r) {
        int row = m0 + wr * 64 + m * 16 + kh * 4 + r;
        int col = n0 + wc * 64 + n * 16 + lrow;
        out[(size_t)row * OUTW + 1 + ks * NN + col] = acc[m][n][r];
      }
}

// ---------------- epilogue: sum split-K partials, expand features ----------------
__global__ __launch_bounds__(512) void epi2_k(float* __restrict__ out) {
  const int r = blockIdx.x;
  const int c = threadIdx.x;  // 0..511
  float* row = out + (size_t)r * OUTW;
  __shared__ float s[NN];
  float xp = row[1 + c] + row[513 + c];   // partial0 (p1 region) + partial1 (p2 region)
  s[c] = xp;
  __syncthreads();
  float p2 = xp * xp;
  float p3 = p2 * xp;
  float sq = sqrtf(fabsf(xp) + 1e-8f);
  float pr = (c < 511) ? s[0] * s[c + 1] : s[1] * s[2];
  if (c == 0) row[0] = 1.0f;
  row[1 + c] = xp;
  row[513 + c] = p2;
  row[1025 + c] = p3;
  row[1537 + c] = pr;
  row[2049 + c] = sq;
}

// ---------------- mid fallback (ws >= 2MB): round-8 gemm (reg-staged A) ----------------
__global__ __launch_bounds__(256) void gemm8(const float* __restrict__ X,
                                             const short* __restrict__ Bt,
                                             float* __restrict__ out) {
  __shared__ short As[2][BM * BK];
  __shared__ short Bs[2][BN * BK];
  const int tid = threadIdx.x;
  const int wid = tid >> 6, lane = tid & 63;
  const int lrow = lane & 15, kh = lane >> 4;
  const int wr = wid >> 1, wc = wid & 1;
  const int bid = blockIdx.x;
  const int s = (bid & 7) * 128 + (bid >> 3);
  const int ks = s >> 9;
  const int tile = s & 511;
  const int m0 = (tile >> 2) * BM;
  const int n0 = (tile & 3) * BN;
  const int kb = ks * KH;
  const int ar0 = tid >> 2, akq = tid & 3;
  const float* aG = X + (size_t)(m0 + ar0) * KK + kb + akq * 8;
  int aoff[2];
#pragma unroll
  for (int j = 0; j < 2; ++j) {
    int row = j * 64 + ar0;
    aoff[j] = row * 32 + ((akq ^ ((row >> 1) & 3)) << 3);
  }
  const int kd = (lane & 3) ^ ((lane >> 3) & 3);
  const short* bG[2];
  int bOff[2];
#pragma unroll
  for (int p = 0; p < 2; ++p) {
    int R0 = (p * 4 + wid) * 16;
    bOff[p] = R0 * 32;
    bG[p] = Bt + (size_t)(n0 + R0 + (lane >> 2)) * KK + kb + kd * 8;
  }
  f32x4 acc[4][4];
#pragma unroll
  for (int m = 0; m < 4; ++m)
#pragma unroll
    for (int n = 0; n < 4; ++n) acc[m][n] = (f32x4)0.0f;
#pragma unroll
  for (int p = 0; p < 2; ++p) gl_lds16(bG[p], &Bs[0][bOff[p]]);
  f32x4 a0 = *(const f32x4*)aG;
  f32x4 a1 = *(const f32x4*)(aG + 4);
  f32x4 a2 = *(const f32x4*)(aG + (size_t)64 * KK);
  f32x4 a3 = *(const f32x4*)(aG + (size_t)64 * KK + 4);
  *(bf16x8*)&As[0][aoff[0]] = cvt8(a0, a1);
  *(bf16x8*)&As[0][aoff[1]] = cvt8(a2, a3);
  a0 = *(const f32x4*)(aG + BK);
  a1 = *(const f32x4*)(aG + BK + 4);
  a2 = *(const f32x4*)(aG + (size_t)64 * KK + BK);
  a3 = *(const f32x4*)(aG + (size_t)64 * KK + BK + 4);
  __syncthreads();
  int cur = 0;
  for (int t = 0; t < NT2; ++t) {
    if (t + 1 < NT2) {
#pragma unroll
      for (int p = 0; p < 2; ++p) gl_lds16(bG[p] + (size_t)(t + 1) * BK, &Bs[cur ^ 1][bOff[p]]);
      *(bf16x8*)&As[cur ^ 1][aoff[0]] = cvt8(a0, a1);
      *(bf16x8*)&As[cur ^ 1][aoff[1]] = cvt8(a2, a3);
      int t2 = (t + 2 < NT2) ? t + 2 : t;
      const float* ap = aG + (size_t)t2 * BK;
      a0 = *(const f32x4*)ap;
      a1 = *(const f32x4*)(ap + 4);
      a2 = *(const f32x4*)(ap + (size_t)64 * KK);
      a3 = *(const f32x4*)(ap + (size_t)64 * KK + 4);
    }
    const int sw = (lrow >> 1) & 3;
    bf16x8 af[4], bfr[4];
#pragma unroll
    for (int m = 0; m < 4; ++m) {
      int r = wr * 64 + m * 16 + lrow;
      af[m] = *(const bf16x8*)&As[cur][r * 32 + ((kh ^ sw) << 3)];
    }
#pragma unroll
    for (int n = 0; n < 4; ++n) {
      int r = wc * 64 + n * 16 + lrow;
      bfr[n] = *(const bf16x8*)&Bs[cur][r * 32 + ((kh ^ sw) << 3)];
    }
#pragma unroll
    for (int m = 0; m < 4; ++m)
#pragma unroll
      for (int n = 0; n < 4; ++n)
        acc[m][n] = __builtin_amdgcn_mfma_f32_16x16x32_bf16(af[m], bfr[n], acc[m][n], 0, 0, 0);
    __syncthreads();
    cur ^= 1;
  }
#pragma unroll
  for (int m = 0; m < 4; ++m)
#pragma unroll
    for (int n = 0; n < 4; ++n)
#pragma unroll
      for (int r = 0; r < 4; ++r) {
        int row = m0 + wr * 64 + m * 16 + kh * 4 + r;
        int col = n0 + wc * 64 + n * 16 + lrow;
        out[(size_t)row * OUTW + 1 + ks * NN + col] = acc[m][n][r];
      }
}

// ---------------- last fallback (no workspace): round-1 path ----------------
#define FBM 128
#define FBN 128
#define FPAD 40

__global__ __launch_bounds__(256) void gemm_k(const float* __restrict__ A,
                                              const float* __restrict__ B,
                                              float* __restrict__ out) {
  __shared__ __align__(16) short Asf[FBM][FPAD];
  __shared__ __align__(16) short Bsf[FBN][FPAD];
  const int tid = threadIdx.x;
  const int bx = blockIdx.x;
  const int m0 = (bx >> 2) * FBM;
  const int n0 = (bx & 3) * FBN;
  const int wid = tid >> 6, lane = tid & 63;
  const int wr = wid >> 1, wc = wid & 1;
  const int lrow = lane & 15, kh = lane >> 4;
  f32x4 acc[4][4];
#pragma unroll
  for (int i = 0; i < 4; i++)
#pragma unroll
    for (int j = 0; j < 4; j++) acc[i][j] = (f32x4)0.0f;
  for (int k0 = 0; k0 < KK; k0 += BK) {
#pragma unroll
    for (int i = 0; i < 4; i++) {
      int fid = i * 256 + tid;
      int ar = fid >> 3, ac = (fid & 7) << 2;
      f32x4 v = *(const f32x4*)(A + (size_t)(m0 + ar) * KK + (k0 + ac));
      short h0 = f2bf(v[0]), h1 = f2bf(v[1]), h2 = f2bf(v[2]), h3 = f2bf(v[3]);
      Asf[ar][ac] = h0; Asf[ar][ac + 1] = h1; Asf[ar][ac + 2] = h2; Asf[ar][ac + 3] = h3;
    }
#pragma unroll
    for (int i = 0; i < 4; i++) {
      int fid = i * 256 + tid;
      int br = fid >> 5, bc = (fid & 31) << 2;
      f32x4 v = *(const f32x4*)(B + (size_t)(k0 + br) * NN + (n0 + bc));
#pragma unroll
      for (int j = 0; j < 4; j++) Bsf[bc + j][br] = f2bf(v[j]);
    }
    __syncthreads();
    bf16x8 af[4], bf[4];
#pragma unroll
    for (int m = 0; m < 4; m++) af[m] = *(const bf16x8*)&Asf[wr * 64 + m * 16 + lrow][kh * 8];
#pragma unroll
    for (int n = 0; n < 4; n++) bf[n] = *(const bf16x8*)&Bsf[wc * 64 + n * 16 + lrow][kh * 8];
#pragma unroll
    for (int m = 0; m < 4; m++)
#pragma unroll
      for (int n = 0; n < 4; n++)
        acc[m][n] = __builtin_amdgcn_mfma_f32_16x16x32_bf16(af[m], bf[n], acc[m][n], 0, 0, 0);
    __syncthreads();
  }
#pragma unroll
  for (int m = 0; m < 4; m++)
#pragma unroll
    for (int n = 0; n < 4; n++)
#pragma unroll
      for (int r = 0; r < 4; r++) {
        int row = m0 + wr * 64 + m * 16 + kh * 4 + r;
        int col = n0 + wc * 64 + n * 16 + lrow;
        out[(size_t)row * OUTW + 1 + col] = acc[m][n][r];
      }
}

__global__ __launch_bounds__(512) void epi_k(float* __restrict__ out) {
  const int r = blockIdx.x;
  const int c = threadIdx.x;
  float* row = out + (size_t)r * OUTW;
  __shared__ float s[NN];
  float xp = row[1 + c];
  s[c] = xp;
  __syncthreads();
  float p2 = xp * xp;
  float p3 = p2 * xp;
  float sq = sqrtf(fabsf(xp) + 1e-8f);
  float pr = (c < 511) ? s[0] * s[c + 1] : s[1] * s[2];
  if (c == 0) row[0] = 1.0f;
  row[513 + c] = p2;
  row[1025 + c] = p3;
  row[1537 + c] = pr;
  row[2049 + c] = sq;
}

extern "C" void kernel_launch(void* const* d_in, const int* in_sizes, int n_in,
                              void* d_out, int out_size, void* d_ws, size_t ws_size,
                              hipStream_t stream) {
  const float* X = (const float*)d_in[0];
  const float* P = (const float*)d_in[1];
  float* out = (float*)d_out;
  (void)in_sizes; (void)n_in; (void)out_size;

  const size_t btBytes = (size_t)NN * KK * sizeof(short);            // 2 MB
  const size_t xbBytes = (size_t)MM * KK * sizeof(short);            // 67.1 MB

  if (ws_size >= btBytes + xbBytes) {
    short* Bt = (short*)d_ws;
    short* Xb = (short*)((char*)d_ws + btBytes);
    prep_b<<<dim3(256), dim3(256), 0, stream>>>(P, Bt);
    xcvt<<<dim3((MM * KK) / (256 * 8)), dim3(256), 0, stream>>>(X, Xb);
    gemm10<<<dim3(1024), dim3(256), 0, stream>>>(Xb, Bt, out);
    epi2_k<<<dim3(MM), dim3(512), 0, stream>>>(out);
  } else if (ws_size >= btBytes) {
    short* Bt = (short*)d_ws;
    prep_b<<<dim3(256), dim3(256), 0, stream>>>(P, Bt);
    gemm8<<<dim3(1024), dim3(256), 0, stream>>>(X, Bt, out);
    epi2_k<<<dim3(MM), dim3(512), 0, stream>>>(out);
  } else {
    gemm_k<<<dim3(512), dim3(256), 0, stream>>>(X, P, out);
    epi_k<<<dim3(MM), dim3(512), 0, stream>>>(out);
  }
}

// Round 11
// 136.353 us; speedup vs baseline: 1.1010x; 1.1010x over previous
//
#include <hip/hip_runtime.h>
#include <hip/hip_bf16.h>
#include <math.h>

// Polynomial feature map: Xp = X @ P; out = [bias | Xp | Xp^2 | Xp^3 | pairs | sqrt(|Xp|+eps)]
// X: [16384, 2048] f32, P: [2048, 512] f32, out: [16384, 2561] f32.
// pairs (triu k=1, first 512): c<511 -> Xp[:,0]*Xp[:,c+1]; c==511 -> Xp[:,1]*Xp[:,2]
//
// Fast path: prep_b (P -> Bt bf16) + xcvt (X -> Xb bf16) in ws; gemm11 = glds-only
// staging + split-K=2 + 2-buffer 2-barrier COUNTED-vmcnt pipeline (stage(t+2) issued
// after the WAR barrier; in-flight prefetch never drained; 32 KB LDS keeps 4 blocks/CU);
// epi2_k sums partials and expands features.

typedef __attribute__((ext_vector_type(4))) float f32x4;
typedef __attribute__((ext_vector_type(8))) short bf16x8;

#define MM 16384
#define NN 512
#define KK 2048
#define OUTW 2561

#define BM 128
#define BN 128
#define BK 32
#define KH (KK / 2)       // 1024 per k-slice
#define NT2 (KH / BK)     // 32 steps

__device__ __forceinline__ short f2bf(float x) {
  union { __hip_bfloat16 b; short s; } u;
  u.b = __float2bfloat16(x);  // hw RNE; compiler pairs into v_cvt_pk_bf16_f32
  return u.s;
}

__device__ __forceinline__ bf16x8 cvt8(f32x4 a, f32x4 b) {
  bf16x8 r;
  r[0] = f2bf(a[0]); r[1] = f2bf(a[1]); r[2] = f2bf(a[2]); r[3] = f2bf(a[3]);
  r[4] = f2bf(b[0]); r[5] = f2bf(b[1]); r[6] = f2bf(b[2]); r[7] = f2bf(b[3]);
  return r;
}

__device__ __forceinline__ void gl_lds16(const void* g, void* l) {
  __builtin_amdgcn_global_load_lds((const __attribute__((address_space(1))) unsigned int*)g,
                                   (__attribute__((address_space(3))) unsigned int*)l, 16, 0, 0);
}

// ---------------- prep: P [K][N] f32 -> Bt [N][K] bf16 ----------------
__global__ __launch_bounds__(256) void prep_b(const float* __restrict__ P, short* __restrict__ Bt) {
  __shared__ float ts[64][65];
  const int tid = threadIdx.x;
  const int k0 = (blockIdx.x >> 3) * 64;  // 32 k-blocks
  const int n0 = (blockIdx.x & 7) * 64;   // 8 n-blocks
#pragma unroll
  for (int j = 0; j < 16; ++j) {
    int idx = j * 256 + tid;
    int kr = idx >> 6, nc = idx & 63;
    ts[kr][nc] = P[(size_t)(k0 + kr) * NN + n0 + nc];
  }
  __syncthreads();
#pragma unroll
  for (int j = 0; j < 16; ++j) {
    int idx = j * 256 + tid;
    int nr = idx >> 6, kc = idx & 63;
    Bt[(size_t)(n0 + nr) * KK + k0 + kc] = f2bf(ts[kc][nr]);
  }
}

// ---------------- xcvt: X [M][K] f32 -> Xb [M][K] bf16 ----------------
__global__ __launch_bounds__(256) void xcvt(const float* __restrict__ X, short* __restrict__ Xb) {
  size_t i = ((size_t)blockIdx.x * 256 + threadIdx.x) * 8;  // grid covers 33.55M elems
  f32x4 a = *(const f32x4*)(X + i);
  f32x4 b = *(const f32x4*)(X + i + 4);
  *(bf16x8*)(Xb + i) = cvt8(a, b);
}

// ---------------- GEMM: glds-only staging + split-K=2 + 2-barrier counted vmcnt ----------------
// LDS tiles [row][32 bf16] (64B rows, 4x 16B slots), phys slot = k-slot ^ ((row>>1)&3)
// -- measured 0 bank conflicts (r3/r4/r6/r8). Both A and B staged only by
// global_load_lds (linear dest); swizzle realized by permuting the per-lane GLOBAL
// source k-slot kd = (lane&3)^((lane>>3)&3) (rule #21).
//
// vmcnt ledger (ONLY vmem ops are 4 glds/iter; no vmem register consumers):
//   prologue: stage(0->b0) + stage(1->b1)                 -> outstanding 8
//   iter t:   s_waitcnt vmcnt(4)  [retires stage(t); stage(t+1) stays in flight]
//             s_barrier           [tile t in LDS for all waves]
//             compute(b[t&1])
//             s_barrier           [WAR: all waves done reading b[t&1]]
//             stage(t+2 -> b[t&1])                        -> outstanding 8
//   tail: t=NT2-2 waits vmcnt(4); t=NT2-1 waits vmcnt(0). No stage, no 2nd barrier.
__global__ __launch_bounds__(256, 4) void gemm11(const short* __restrict__ Xb,
                                                 const short* __restrict__ Bt,
                                                 float* __restrict__ out) {
  __shared__ short As[2][BM * BK];   // 8 KB each
  __shared__ short Bs[2][BN * BK];   // 8 KB each  (32 KB total -> 4 blocks/CU)

  const int tid = threadIdx.x;
  const int wid = tid >> 6, lane = tid & 63;
  const int lrow = lane & 15, kh = lane >> 4;
  const int wr = wid >> 1, wc = wid & 1;  // 2x2 wave grid; wave tile 64 x 64

  // XCD-bijective swizzle over 1024 blocks (1024%8==0). s<512 -> ks=0 (XCDs 0-3),
  // s>=512 -> ks=1 (XCDs 4-7): each XCD's K-half of Bt (1 MB) fits its private L2.
  const int bid = blockIdx.x;
  const int s = (bid & 7) * 128 + (bid >> 3);
  const int ks = s >> 9;
  const int tile = s & 511;
  const int m0 = (tile >> 2) * BM;   // 128 row-blocks
  const int n0 = (tile & 3) * BN;    // 4 col-blocks (consecutive tiles share A rows)
  const int kb = ks * KH;

  // staging descriptors: 2 A-loads + 2 B-loads per wave; load p covers rows (p*4+wid)*16..+15
  const int kd = (lane & 3) ^ ((lane >> 3) & 3);  // pre-swizzled source k-slot
  const short* aG[2];
  const short* bG[2];
  int tOff[2];
#pragma unroll
  for (int p = 0; p < 2; ++p) {
    int R0 = (p * 4 + wid) * 16;
    tOff[p] = R0 * 32;  // linear dest (shorts); hw adds lane*16B
    aG[p] = Xb + (size_t)(m0 + R0 + (lane >> 2)) * KK + kb + kd * 8;
    bG[p] = Bt + (size_t)(n0 + R0 + (lane >> 2)) * KK + kb + kd * 8;
  }

  f32x4 acc[4][4];
#pragma unroll
  for (int m = 0; m < 4; ++m)
#pragma unroll
    for (int n = 0; n < 4; ++n) acc[m][n] = (f32x4)0.0f;

  auto stage = [&](int t, int b) {
#pragma unroll
    for (int p = 0; p < 2; ++p) gl_lds16(aG[p] + (size_t)t * BK, &As[b][tOff[p]]);
#pragma unroll
    for (int p = 0; p < 2; ++p) gl_lds16(bG[p] + (size_t)t * BK, &Bs[b][tOff[p]]);
  };
  auto compute = [&](int b) {
    const int sw = (lrow >> 1) & 3;
    bf16x8 af[4], bfr[4];
#pragma unroll
    for (int m = 0; m < 4; ++m) {
      int r = wr * 64 + m * 16 + lrow;
      af[m] = *(const bf16x8*)&As[b][r * 32 + ((kh ^ sw) << 3)];
    }
#pragma unroll
    for (int n = 0; n < 4; ++n) {
      int r = wc * 64 + n * 16 + lrow;
      bfr[n] = *(const bf16x8*)&Bs[b][r * 32 + ((kh ^ sw) << 3)];
    }
#pragma unroll
    for (int m = 0; m < 4; ++m)
#pragma unroll
      for (int n = 0; n < 4; ++n)
        acc[m][n] = __builtin_amdgcn_mfma_f32_16x16x32_bf16(af[m], bfr[n], acc[m][n], 0, 0, 0);
  };

  // ---- prologue: 2 tiles in flight ----
  stage(0, 0);
  stage(1, 1);

  // ---- main loop ----
  for (int t = 0; t < NT2 - 2; ++t) {
    asm volatile("s_waitcnt vmcnt(4)" ::: "memory");  // retire stage(t); keep stage(t+1)
    __builtin_amdgcn_s_barrier();                     // tile t landed for all waves
    compute(t & 1);
    __builtin_amdgcn_s_barrier();                     // WAR: all done reading buf[t&1]
    stage(t + 2, t & 1);
  }
  // tail: t = NT2-2 (outstanding: stage(NT2-2), stage(NT2-1))
  asm volatile("s_waitcnt vmcnt(4)" ::: "memory");
  __builtin_amdgcn_s_barrier();
  compute((NT2 - 2) & 1);
  // tail: t = NT2-1 (outstanding: stage(NT2-1))
  asm volatile("s_waitcnt vmcnt(0)" ::: "memory");
  __builtin_amdgcn_s_barrier();
  compute((NT2 - 1) & 1);

  // ---- write partial Xp into region ks (C/D layout: col = lane&15, row = kh*4 + reg) ----
#pragma unroll
  for (int m = 0; m < 4; ++m)
#pragma unroll
    for (int n = 0; n < 4; ++n)
#pragma unroll
      for (int r = 0; r < 4; ++r) {
        int row = m0 + wr * 64 + m * 16 + kh * 4 + r;
        int col = n0 + wc * 64 + n * 16 + lrow;
        out[(size_t)row * OUTW + 1 + ks * NN + col] = acc[m][n][r];
      }
}

// ---------------- epilogue: sum split-K partials, expand features ----------------
__global__ __launch_bounds__(512) void epi2_k(float* __restrict__ out) {
  const int r = blockIdx.x;
  const int c = threadIdx.x;  // 0..511
  float* row = out + (size_t)r * OUTW;
  __shared__ float s[NN];
  float xp = row[1 + c] + row[513 + c];   // partial0 (p1 region) + partial1 (p2 region)
  s[c] = xp;
  __syncthreads();
  float p2 = xp * xp;
  float p3 = p2 * xp;
  float sq = sqrtf(fabsf(xp) + 1e-8f);
  float pr = (c < 511) ? s[0] * s[c + 1] : s[1] * s[2];
  if (c == 0) row[0] = 1.0f;
  row[1 + c] = xp;
  row[513 + c] = p2;
  row[1025 + c] = p3;
  row[1537 + c] = pr;
  row[2049 + c] = sq;
}

// ---------------- mid fallback (ws >= 2MB): round-8 gemm (reg-staged A) ----------------
__global__ __launch_bounds__(256) void gemm8(const float* __restrict__ X,
                                             const short* __restrict__ Bt,
                                             float* __restrict__ out) {
  __shared__ short As[2][BM * BK];
  __shared__ short Bs[2][BN * BK];
  const int tid = threadIdx.x;
  const int wid = tid >> 6, lane = tid & 63;
  const int lrow = lane & 15, kh = lane >> 4;
  const int wr = wid >> 1, wc = wid & 1;
  const int bid = blockIdx.x;
  const int s = (bid & 7) * 128 + (bid >> 3);
  const int ks = s >> 9;
  const int tile = s & 511;
  const int m0 = (tile >> 2) * BM;
  const int n0 = (tile & 3) * BN;
  const int kb = ks * KH;
  const int ar0 = tid >> 2, akq = tid & 3;
  const float* aG = X + (size_t)(m0 + ar0) * KK + kb + akq * 8;
  int aoff[2];
#pragma unroll
  for (int j = 0; j < 2; ++j) {
    int row = j * 64 + ar0;
    aoff[j] = row * 32 + ((akq ^ ((row >> 1) & 3)) << 3);
  }
  const int kd = (lane & 3) ^ ((lane >> 3) & 3);
  const short* bG[2];
  int bOff[2];
#pragma unroll
  for (int p = 0; p < 2; ++p) {
    int R0 = (p * 4 + wid) * 16;
    bOff[p] = R0 * 32;
    bG[p] = Bt + (size_t)(n0 + R0 + (lane >> 2)) * KK + kb + kd * 8;
  }
  f32x4 acc[4][4];
#pragma unroll
  for (int m = 0; m < 4; ++m)
#pragma unroll
    for (int n = 0; n < 4; ++n) acc[m][n] = (f32x4)0.0f;
#pragma unroll
  for (int p = 0; p < 2; ++p) gl_lds16(bG[p], &Bs[0][bOff[p]]);
  f32x4 a0 = *(const f32x4*)aG;
  f32x4 a1 = *(const f32x4*)(aG + 4);
  f32x4 a2 = *(const f32x4*)(aG + (size_t)64 * KK);
  f32x4 a3 = *(const f32x4*)(aG + (size_t)64 * KK + 4);
  *(bf16x8*)&As[0][aoff[0]] = cvt8(a0, a1);
  *(bf16x8*)&As[0][aoff[1]] = cvt8(a2, a3);
  a0 = *(const f32x4*)(aG + BK);
  a1 = *(const f32x4*)(aG + BK + 4);
  a2 = *(const f32x4*)(aG + (size_t)64 * KK + BK);
  a3 = *(const f32x4*)(aG + (size_t)64 * KK + BK + 4);
  __syncthreads();
  int cur = 0;
  for (int t = 0; t < NT2; ++t) {
    if (t + 1 < NT2) {
#pragma unroll
      for (int p = 0; p < 2; ++p) gl_lds16(bG[p] + (size_t)(t + 1) * BK, &Bs[cur ^ 1][bOff[p]]);
      *(bf16x8*)&As[cur ^ 1][aoff[0]] = cvt8(a0, a1);
      *(bf16x8*)&As[cur ^ 1][aoff[1]] = cvt8(a2, a3);
      int t2 = (t + 2 < NT2) ? t + 2 : t;
      const float* ap = aG + (size_t)t2 * BK;
      a0 = *(const f32x4*)ap;
      a1 = *(const f32x4*)(ap + 4);
      a2 = *(const f32x4*)(ap + (size_t)64 * KK);
      a3 = *(const f32x4*)(ap + (size_t)64 * KK + 4);
    }
    const int sw = (lrow >> 1) & 3;
    bf16x8 af[4], bfr[4];
#pragma unroll
    for (int m = 0; m < 4; ++m) {
      int r = wr * 64 + m * 16 + lrow;
      af[m] = *(const bf16x8*)&As[cur][r * 32 + ((kh ^ sw) << 3)];
    }
#pragma unroll
    for (int n = 0; n < 4; ++n) {
      int r = wc * 64 + n * 16 + lrow;
      bfr[n] = *(const bf16x8*)&Bs[cur][r * 32 + ((kh ^ sw) << 3)];
    }
#pragma unroll
    for (int m = 0; m < 4; ++m)
#pragma unroll
      for (int n = 0; n < 4; ++n)
        acc[m][n] = __builtin_amdgcn_mfma_f32_16x16x32_bf16(af[m], bfr[n], acc[m][n], 0, 0, 0);
    __syncthreads();
    cur ^= 1;
  }
#pragma unroll
  for (int m = 0; m < 4; ++m)
#pragma unroll
    for (int n = 0; n < 4; ++n)
#pragma unroll
      for (int r = 0; r < 4; ++r) {
        int row = m0 + wr * 64 + m * 16 + kh * 4 + r;
        int col = n0 + wc * 64 + n * 16 + lrow;
        out[(size_t)row * OUTW + 1 + ks * NN + col] = acc[m][n][r];
      }
}

// ---------------- last fallback (no workspace): round-1 path ----------------
#define FBM 128
#define FBN 128
#define FPAD 40

__global__ __launch_bounds__(256) void gemm_k(const float* __restrict__ A,
                                              const float* __restrict__ B,
                                              float* __restrict__ out) {
  __shared__ __align__(16) short Asf[FBM][FPAD];
  __shared__ __align__(16) short Bsf[FBN][FPAD];
  const int tid = threadIdx.x;
  const int bx = blockIdx.x;
  const int m0 = (bx >> 2) * FBM;
  const int n0 = (bx & 3) * FBN;
  const int wid = tid >> 6, lane = tid & 63;
  const int wr = wid >> 1, wc = wid & 1;
  const int lrow = lane & 15, kh = lane >> 4;
  f32x4 acc[4][4];
#pragma unroll
  for (int i = 0; i < 4; i++)
#pragma unroll
    for (int j = 0; j < 4; j++) acc[i][j] = (f32x4)0.0f;
  for (int k0 = 0; k0 < KK; k0 += BK) {
#pragma unroll
    for (int i = 0; i < 4; i++) {
      int fid = i * 256 + tid;
      int ar = fid >> 3, ac = (fid & 7) << 2;
      f32x4 v = *(const f32x4*)(A + (size_t)(m0 + ar) * KK + (k0 + ac));
      short h0 = f2bf(v[0]), h1 = f2bf(v[1]), h2 = f2bf(v[2]), h3 = f2bf(v[3]);
      Asf[ar][ac] = h0; Asf[ar][ac + 1] = h1; Asf[ar][ac + 2] = h2; Asf[ar][ac + 3] = h3;
    }
#pragma unroll
    for (int i = 0; i < 4; i++) {
      int fid = i * 256 + tid;
      int br = fid >> 5, bc = (fid & 31) << 2;
      f32x4 v = *(const f32x4*)(B + (size_t)(k0 + br) * NN + (n0 + bc));
#pragma unroll
      for (int j = 0; j < 4; j++) Bsf[bc + j][br] = f2bf(v[j]);
    }
    __syncthreads();
    bf16x8 af[4], bf[4];
#pragma unroll
    for (int m = 0; m < 4; m++) af[m] = *(const bf16x8*)&Asf[wr * 64 + m * 16 + lrow][kh * 8];
#pragma unroll
    for (int n = 0; n < 4; n++) bf[n] = *(const bf16x8*)&Bsf[wc * 64 + n * 16 + lrow][kh * 8];
#pragma unroll
    for (int m = 0; m < 4; m++)
#pragma unroll
      for (int n = 0; n < 4; n++)
        acc[m][n] = __builtin_amdgcn_mfma_f32_16x16x32_bf16(af[m], bf[n], acc[m][n], 0, 0, 0);
    __syncthreads();
  }
#pragma unroll
  for (int m = 0; m < 4; m++)
#pragma unroll
    for (int n = 0; n < 4; n++)
#pragma unroll
      for (int r = 0; r < 4; r++) {
        int row = m0 + wr * 64 + m * 16 + kh * 4 + r;
        int col = n0 + wc * 64 + n * 16 + lrow;
        out[(size_t)row * OUTW + 1 + col] = acc[m][n][r];
      }
}

__global__ __launch_bounds__(512) void epi_k(float* __restrict__ out) {
  const int r = blockIdx.x;
  const int c = threadIdx.x;
  float* row = out + (size_t)r * OUTW;
  __shared__ float s[NN];
  float xp = row[1 + c];
  s[c] = xp;
  __syncthreads();
  float p2 = xp * xp;
  float p3 = p2 * xp;
  float sq = sqrtf(fabsf(xp) + 1e-8f);
  float pr = (c < 511) ? s[0] * s[c + 1] : s[1] * s[2];
  if (c == 0) row[0] = 1.0f;
  row[513 + c] = p2;
  row[1025 + c] = p3;
  row[1537 + c] = pr;
  row[2049 + c] = sq;
}

extern "C" void kernel_launch(void* const* d_in, const int* in_sizes, int n_in,
                              void* d_out, int out_size, void* d_ws, size_t ws_size,
                              hipStream_t stream) {
  const float* X = (const float*)d_in[0];
  const float* P = (const float*)d_in[1];
  float* out = (float*)d_out;
  (void)in_sizes; (void)n_in; (void)out_size;

  const size_t btBytes = (size_t)NN * KK * sizeof(short);            // 2 MB
  const size_t xbBytes = (size_t)MM * KK * sizeof(short);            // 67.1 MB

  if (ws_size >= btBytes + xbBytes) {
    short* Bt = (short*)d_ws;
    short* Xb = (short*)((char*)d_ws + btBytes);
    prep_b<<<dim3(256), dim3(256), 0, stream>>>(P, Bt);
    xcvt<<<dim3((MM * KK) / (256 * 8)), dim3(256), 0, stream>>>(X, Xb);
    gemm11<<<dim3(1024), dim3(256), 0, stream>>>(Xb, Bt, out);
    epi2_k<<<dim3(MM), dim3(512), 0, stream>>>(out);
  } else if (ws_size >= btBytes) {
    short* Bt = (short*)d_ws;
    prep_b<<<dim3(256), dim3(256), 0, stream>>>(P, Bt);
    gemm8<<<dim3(1024), dim3(256), 0, stream>>>(X, Bt, out);
    epi2_k<<<dim3(MM), dim3(512), 0, stream>>>(out);
  } else {
    gemm_k<<<dim3(512), dim3(256), 0, stream>>>(X, P, out);
    epi_k<<<dim3(MM), dim3(512), 0, stream>>>(out);
  }
}